// Round 3
// baseline (347.392 us; speedup 1.0000x reference)
//
#include <hip/hip_runtime.h>
#include <math.h>

#define LL    3264
#define KK    12
#define PP    32           // total ports = 8*4
#define NW    21           // delay search window size (DMAX-DMIN+1)
#define DMIN  (-10)
#define GAVG  (LL/4)       // 816, after OCC averaging (LOCC=4)
#define NBLK  (LL/12)      // 272 MMSE blocks

#define OUT_REAL  (PP*PP*LL)      // 3,342,336  (harness compares real part, fp32)
#define OUT_CPLX  (PP*PP*LL*2)    // 6,684,672  (interleaved re/im)
#define SCRATCH_F 270520          // floats of scratch (8B-aligned count)

// ---------------------------------------------------------------------------
// Kernel 1: per-(port,window-pos) direct DFT magnitude^2 (double accum),
//           plus one extra block for noise power.
// ---------------------------------------------------------------------------
__global__ void k_window_noise(const float* __restrict__ lsr,
                               const float* __restrict__ lsi,
                               const int* __restrict__ cs,
                               double* __restrict__ mag2,
                               double* __restrict__ noise) {
    __shared__ double sre[256], sim[256];
    const int b = blockIdx.x;
    const int tid = threadIdx.x;
    if (b < PP * NW) {
        const int p = b / NW, r = b % NW;
        const int ideal = ((KK - cs[p]) % KK) * (LL / KK);
        int t = ideal + DMIN + r;
        t %= LL; if (t < 0) t += LL;
        double are = 0.0, aim = 0.0;
        for (int n = tid; n < LL; n += 256) {
            long mod = ((long)n * (long)t) % LL;
            double ang = (2.0 * M_PI / (double)LL) * (double)mod;
            double ss, cc;
            sincos(ang, &ss, &cc);
            double xr = lsr[n], xi = lsi[n];
            are += xr * cc - xi * ss;   // ls[n]*exp(+i ang); 1/L scale dropped
            aim += xr * ss + xi * cc;
        }
        sre[tid] = are; sim[tid] = aim;
        __syncthreads();
        for (int s = 128; s > 0; s >>= 1) {
            if (tid < s) { sre[tid] += sre[tid + s]; sim[tid] += sim[tid + s]; }
            __syncthreads();
        }
        if (tid == 0) mag2[b] = sre[0] * sre[0] + sim[0] * sim[0];
    } else {
        double acc = 0.0;
        for (int n = tid; n < LL - 1; n += 256) {
            double dr = (double)lsr[n + 1] - (double)lsr[n];
            double di = (double)lsi[n + 1] - (double)lsi[n];
            acc += dr * dr + di * di;
        }
        sre[tid] = acc;
        __syncthreads();
        for (int s = 128; s > 0; s >>= 1) {
            if (tid < s) sre[tid] += sre[tid + s];
            __syncthreads();
        }
        if (tid == 0) *noise = sre[0] / (double)(LL - 1) * 0.5;
    }
}

// ---------------------------------------------------------------------------
// Kernel 2: per-port argmax -> peak[p] (m == peak mod L determines phasor);
//           thread 0 builds the 12x12 MMSE filter F = C * inv(A).
// ---------------------------------------------------------------------------
__global__ void k_peak_F(const int* __restrict__ cs,
                         const double* __restrict__ mag2,
                         const double* __restrict__ noise,
                         int* __restrict__ peak,
                         float* __restrict__ F) {
    const int tid = threadIdx.x;
    if (tid < PP) {
        const int ideal = ((KK - cs[tid]) % KK) * (LL / KK);
        double best = -1.0; int bestl = 0x7fffffff;
        for (int r = 0; r < NW; r++) {
            int l = ideal + DMIN + r;
            l %= LL; if (l < 0) l += LL;
            double v = mag2[tid * NW + r];
            if (v > best || (v == best && l < bestl)) { best = v; bestl = l; }
        }
        peak[tid] = bestl;
    }
    if (tid == 0) {
        double A[12][12], Y[12][12];
        const double npow = (double)((float)(*noise));
        for (int i = 0; i < 12; i++)
            for (int j = 0; j < 12; j++) {
                int d = i - j; if (d < 0) d = -d;
                float cij = (float)pow(0.9, (double)d);
                A[i][j] = (double)cij + (i == j ? npow : 0.0);
                Y[i][j] = (double)cij;            // solve A*Y = C
            }
        for (int col = 0; col < 12; col++) {
            int piv = col; double mx = fabs(A[col][col]);
            for (int r = col + 1; r < 12; r++)
                if (fabs(A[r][col]) > mx) { mx = fabs(A[r][col]); piv = r; }
            if (piv != col)
                for (int j = 0; j < 12; j++) {
                    double t = A[col][j]; A[col][j] = A[piv][j]; A[piv][j] = t;
                    t = Y[col][j]; Y[col][j] = Y[piv][j]; Y[piv][j] = t;
                }
            double dinv = 1.0 / A[col][col];
            for (int j = 0; j < 12; j++) { A[col][j] *= dinv; Y[col][j] *= dinv; }
            for (int r = 0; r < 12; r++)
                if (r != col) {
                    double f = A[r][col];
                    if (f != 0.0)
                        for (int j = 0; j < 12; j++) {
                            A[r][j] -= f * A[col][j];
                            Y[r][j] -= f * Y[col][j];
                        }
                }
        }
        // F = C*inv(A); A,C symmetric => F[j][k] = Y[k][j]
        for (int j = 0; j < 12; j++)
            for (int k = 0; k < 12; k++)
                F[j * 12 + k] = (float)Y[k][j];
    }
}

// ---------------------------------------------------------------------------
// Kernel 3: h_avg[p][jj] = mean over 4 of ls[n]*phasor[p][n]
// ---------------------------------------------------------------------------
__global__ void k_havg(const float* __restrict__ lsr, const float* __restrict__ lsi,
                       const int* __restrict__ peak, float* __restrict__ havg) {
    const int idx = blockIdx.x * blockDim.x + threadIdx.x;
    if (idx >= PP * GAVG) return;
    const int p = idx / GAVG, jj = idx % GAVG;
    const int m = peak[p];
    const float c0 = (float)(2.0 * M_PI / (double)LL);
    float ar = 0.f, ai = 0.f;
    for (int s = 0; s < 4; s++) {
        int n = jj * 4 + s;
        int mod = (int)(((long)m * (long)n) % LL);
        float ph = c0 * (float)mod;
        float ss, cc;
        sincosf(ph, &ss, &cc);
        float xr = lsr[n], xi = lsi[n];
        ar += xr * cc - xi * ss;
        ai += xr * ss + xi * cc;
    }
    havg[idx * 2]     = ar * 0.25f;
    havg[idx * 2 + 1] = ai * 0.25f;
}

// ---------------------------------------------------------------------------
// Kernel 4: linear interp back to L (samples at 1.5+4j, clamped ends)
// ---------------------------------------------------------------------------
__global__ void k_interp(const float* __restrict__ havg, float* __restrict__ hinterp) {
    const int idx = blockIdx.x * blockDim.x + threadIdx.x;
    if (idx >= PP * LL) return;
    const int p = idx / LL, x = idx % LL;
    const float* hp = havg + (size_t)p * GAVG * 2;
    float re, im;
    if (x < 2) { re = hp[0]; im = hp[1]; }
    else if (x >= LL - 2) { re = hp[(GAVG - 1) * 2]; im = hp[(GAVG - 1) * 2 + 1]; }
    else {
        int j = (x - 2) >> 2;
        float t = ((float)x - (1.5f + 4.0f * (float)j)) * 0.25f;
        float r0 = hp[j * 2],       i0 = hp[j * 2 + 1];
        float r1 = hp[(j + 1) * 2], i1 = hp[(j + 1) * 2 + 1];
        re = r0 + t * (r1 - r0);
        im = i0 + t * (i1 - i0);
    }
    hinterp[idx * 2]     = re;
    hinterp[idx * 2 + 1] = im;
}

// ---------------------------------------------------------------------------
// Kernel 5: residual[l] = ls[l] - sum_p h_interp[p][l] / phasor[p][l]
// ---------------------------------------------------------------------------
__global__ void k_resid(const float* __restrict__ lsr, const float* __restrict__ lsi,
                        const int* __restrict__ peak, const float* __restrict__ hinterp,
                        float* __restrict__ resid) {
    const int l = blockIdx.x * blockDim.x + threadIdx.x;
    if (l >= LL) return;
    const float c0 = (float)(2.0 * M_PI / (double)LL);
    float sr = 0.f, si = 0.f;
    for (int p = 0; p < PP; p++) {
        int m = peak[p];
        int mod = (int)(((long)m * (long)l) % LL);
        float ph = c0 * (float)mod;
        float ss, cc;
        sincosf(ph, &ss, &cc);
        float hr = hinterp[((size_t)p * LL + l) * 2];
        float hi = hinterp[((size_t)p * LL + l) * 2 + 1];
        float den = cc * cc + ss * ss;
        sr += (hr * cc + hi * ss) / den;
        si += (hi * cc - hr * ss) / den;
    }
    resid[l * 2]     = lsr[l] - sr;
    resid[l * 2 + 1] = lsi[l] - si;
}

// ---------------------------------------------------------------------------
// Kernel 6: h_wr = h_interp + residual*phasor; block-MMSE with F; write
//           h_mmse tile 0. CPLX: interleaved re/im. !CPLX: real part only.
// ---------------------------------------------------------------------------
template <bool CPLX>
__global__ void k_mmse(const int* __restrict__ peak, const float* __restrict__ hinterp,
                       const float* __restrict__ resid, const float* __restrict__ F,
                       float* __restrict__ out) {
    const int idx = blockIdx.x * blockDim.x + threadIdx.x;
    if (idx >= PP * NBLK) return;
    const int p = idx / NBLK, b = idx % NBLK;
    const int m = peak[p];
    const float c0 = (float)(2.0 * M_PI / (double)LL);
    float wr[12], wi[12];
    for (int k = 0; k < 12; k++) {
        int n = b * 12 + k;
        int mod = (int)(((long)m * (long)n) % LL);
        float ph = c0 * (float)mod;
        float ss, cc;
        sincosf(ph, &ss, &cc);
        float rr = resid[n * 2], ri = resid[n * 2 + 1];
        wr[k] = hinterp[((size_t)p * LL + n) * 2]     + (rr * cc - ri * ss);
        wi[k] = hinterp[((size_t)p * LL + n) * 2 + 1] + (rr * ss + ri * cc);
    }
    for (int j = 0; j < 12; j++) {
        float ar = 0.f, ai = 0.f;
        for (int k = 0; k < 12; k++) {
            float f = F[j * 12 + k];
            ar += f * wr[k];
            ai += f * wi[k];
        }
        if (CPLX) {
            float* orow = out + (size_t)p * LL * 2 + (size_t)b * 24;
            orow[j * 2]     = ar;
            orow[j * 2 + 1] = ai;
        } else {
            out[(size_t)p * LL + (size_t)b * 12 + j] = ar;
        }
    }
}

// ---------------------------------------------------------------------------
// Kernel 7: tile block 0 to the remaining (P-1) copies (overwrites any
//           scratch living in the output tail; all scratch reads are done).
//           TILEF = floats per tile (must be multiple of 4).
// ---------------------------------------------------------------------------
__global__ void k_tile(float4* __restrict__ out, int tile_f4) {
    const int idx = blockIdx.x * blockDim.x + threadIdx.x;
    if (idx >= tile_f4) return;
    float4 v = out[idx];
    for (int q = 1; q < PP; q++)
        out[(size_t)q * tile_f4 + idx] = v;
}

extern "C" void kernel_launch(void* const* d_in, const int* in_sizes, int n_in,
                              void* d_out, int out_size, void* d_ws, size_t ws_size,
                              hipStream_t stream) {
    const float* lsr = (const float*)d_in[0];
    const float* lsi = (const float*)d_in[1];
    const int*   cs  = (const int*)d_in[2];
    float* out = (float*)d_out;

    const bool cplx = (out_size >= OUT_CPLX);

    // ---- scratch: prefer d_ws when verifiably big enough, else out tail ----
    float* base;
    if (ws_size >= (size_t)SCRATCH_F * sizeof(float)) {
        base = (float*)d_ws;
    } else {
        base = out + ((size_t)out_size - SCRATCH_F);   // consumed before k_tile
    }
    // layout (float offsets): mag2[672 dbl]=1344f, noise[1 dbl]=2f @1344,
    // peak[32 i32]@2692, F[144 f32]@2724, havg[52224]@2868,
    // hint[208896]@55092, resid[6528]@263988 -> end 270516 (<270520)
    double* mag2  = (double*)base;
    double* noise = mag2 + PP * NW;
    int*    peak  = (int*)(base + 2692);
    float*  F     = base + 2724;
    float*  havg  = base + 2868;
    float*  hint  = base + 55092;
    float*  resid = base + 263988;

    k_window_noise<<<PP * NW + 1, 256, 0, stream>>>(lsr, lsi, cs, mag2, noise);
    k_peak_F<<<1, 64, 0, stream>>>(cs, mag2, noise, peak, F);
    k_havg<<<(PP * GAVG + 255) / 256, 256, 0, stream>>>(lsr, lsi, peak, havg);
    k_interp<<<(PP * LL + 255) / 256, 256, 0, stream>>>(havg, hint);
    k_resid<<<(LL + 255) / 256, 256, 0, stream>>>(lsr, lsi, peak, hint, resid);

    if (cplx) {
        k_mmse<true><<<(PP * NBLK + 255) / 256, 256, 0, stream>>>(peak, hint, resid, F, out);
        const int tile_f4 = PP * LL * 2 / 4;   // 52,224 float4 per tile
        k_tile<<<(tile_f4 + 255) / 256, 256, 0, stream>>>((float4*)out, tile_f4);
    } else {
        k_mmse<false><<<(PP * NBLK + 255) / 256, 256, 0, stream>>>(peak, hint, resid, F, out);
        const int tile_f4 = PP * LL / 4;       // 26,112 float4 per tile
        k_tile<<<(tile_f4 + 255) / 256, 256, 0, stream>>>((float4*)out, tile_f4);
    }
}

// Round 4
// 56.249 us; speedup vs baseline: 6.1759x; 6.1759x over previous
//
#include <hip/hip_runtime.h>
#include <math.h>

#define LL    3264
#define KK    12
#define PP    32           // total ports = 8*4
#define NW    21           // delay search window size (DMAX-DMIN+1)
#define DMIN  (-10)
#define GAVG  (LL/4)       // 816, after OCC averaging (LOCC=4)
#define NBLK  (LL/12)      // 272 MMSE blocks

#define OUT_REAL  (PP*PP*LL)      // 3,342,336  (harness compares real part, fp32)
#define OUT_CPLX  (PP*PP*LL*2)    // 6,684,672  (interleaved re/im)
#define SCRATCH_F 270520          // floats of scratch (8B-aligned count)

// ---------------------------------------------------------------------------
// Kernel 1: per-(port,window-pos) direct DFT magnitude^2 (double accum),
//           plus one extra block for noise power.
// ---------------------------------------------------------------------------
__global__ void k_window_noise(const float* __restrict__ lsr,
                               const float* __restrict__ lsi,
                               const int* __restrict__ cs,
                               double* __restrict__ mag2,
                               double* __restrict__ noise) {
    __shared__ double sre[256], sim[256];
    const int b = blockIdx.x;
    const int tid = threadIdx.x;
    if (b < PP * NW) {
        const int p = b / NW, r = b % NW;
        const int ideal = ((KK - cs[p]) % KK) * (LL / KK);
        int t = ideal + DMIN + r;
        t %= LL; if (t < 0) t += LL;
        double are = 0.0, aim = 0.0;
        for (int n = tid; n < LL; n += 256) {
            long mod = ((long)n * (long)t) % LL;
            double ang = (2.0 * M_PI / (double)LL) * (double)mod;
            double ss, cc;
            sincos(ang, &ss, &cc);
            double xr = lsr[n], xi = lsi[n];
            are += xr * cc - xi * ss;   // ls[n]*exp(+i ang); 1/L scale dropped
            aim += xr * ss + xi * cc;
        }
        sre[tid] = are; sim[tid] = aim;
        __syncthreads();
        for (int s = 128; s > 0; s >>= 1) {
            if (tid < s) { sre[tid] += sre[tid + s]; sim[tid] += sim[tid + s]; }
            __syncthreads();
        }
        if (tid == 0) mag2[b] = sre[0] * sre[0] + sim[0] * sim[0];
    } else {
        double acc = 0.0;
        for (int n = tid; n < LL - 1; n += 256) {
            double dr = (double)lsr[n + 1] - (double)lsr[n];
            double di = (double)lsi[n + 1] - (double)lsi[n];
            acc += dr * dr + di * di;
        }
        sre[tid] = acc;
        __syncthreads();
        for (int s = 128; s > 0; s >>= 1) {
            if (tid < s) sre[tid] += sre[tid + s];
            __syncthreads();
        }
        if (tid == 0) *noise = sre[0] / (double)(LL - 1) * 0.5;
    }
}

// ---------------------------------------------------------------------------
// Kernel 2: per-port argmax -> peak[p] (threads 0..31), and parallel 12x12
//           Gauss-Jordan in shared memory (threads 0..143) for F = C*inv(A).
//           A is SPD (KMS matrix + noise*I) -> no pivoting needed.
// ---------------------------------------------------------------------------
__global__ void k_peak_F(const int* __restrict__ cs,
                         const double* __restrict__ mag2,
                         const double* __restrict__ noise,
                         int* __restrict__ peak,
                         float* __restrict__ F) {
    __shared__ double A[12][12], Y[12][12];
    const int tid = threadIdx.x;

    if (tid < PP) {
        const int ideal = ((KK - cs[tid]) % KK) * (LL / KK);
        double best = -1.0; int bestl = 0x7fffffff;
        for (int r = 0; r < NW; r++) {
            int l = ideal + DMIN + r;
            l %= LL; if (l < 0) l += LL;
            double v = mag2[tid * NW + r];
            if (v > best || (v == best && l < bestl)) { best = v; bestl = l; }
        }
        peak[tid] = bestl;
    }

    const int row = tid / 12, c = tid % 12;
    if (tid < 144) {
        int d = row - c; if (d < 0) d = -d;
        float cij = (float)pow(0.9, (double)d);          // C is fp32 in reference
        double npow = (double)((float)(*noise));         // reference noise is fp32
        A[row][c] = (double)cij + (row == c ? npow : 0.0);
        Y[row][c] = (double)cij;                         // solve A*Y = C
    }
    __syncthreads();

    for (int col = 0; col < 12; col++) {
        double dinv = 0.0, pa = 0.0, py = 0.0, f = 0.0;
        if (tid < 144) {
            dinv = 1.0 / A[col][col];
            pa = A[col][c]; py = Y[col][c];              // old pivot row
            f  = A[row][col];
        }
        __syncthreads();                                 // all reads before writes
        if (tid < 144) {
            if (row == col) { A[row][c] = pa * dinv; Y[row][c] = py * dinv; }
            else            { A[row][c] -= (f * dinv) * pa; Y[row][c] -= (f * dinv) * py; }
        }
        __syncthreads();
    }

    // F = C*inv(A); A,C symmetric => F[j][k] = (inv(A)*C)[k][j] = Y[k][j]
    if (tid < 144) F[row * 12 + c] = (float)Y[c][row];
}

// ---------------------------------------------------------------------------
// Kernel 3: h_avg[p][jj] = mean over 4 of ls[n]*phasor[p][n]
// ---------------------------------------------------------------------------
__global__ void k_havg(const float* __restrict__ lsr, const float* __restrict__ lsi,
                       const int* __restrict__ peak, float* __restrict__ havg) {
    const int idx = blockIdx.x * blockDim.x + threadIdx.x;
    if (idx >= PP * GAVG) return;
    const int p = idx / GAVG, jj = idx % GAVG;
    const int m = peak[p];
    const float c0 = (float)(2.0 * M_PI / (double)LL);
    float ar = 0.f, ai = 0.f;
    for (int s = 0; s < 4; s++) {
        int n = jj * 4 + s;
        int mod = (int)(((long)m * (long)n) % LL);
        float ph = c0 * (float)mod;
        float ss, cc;
        sincosf(ph, &ss, &cc);
        float xr = lsr[n], xi = lsi[n];
        ar += xr * cc - xi * ss;
        ai += xr * ss + xi * cc;
    }
    havg[idx * 2]     = ar * 0.25f;
    havg[idx * 2 + 1] = ai * 0.25f;
}

// ---------------------------------------------------------------------------
// Kernel 4: linear interp back to L (samples at 1.5+4j, clamped ends)
// ---------------------------------------------------------------------------
__global__ void k_interp(const float* __restrict__ havg, float* __restrict__ hinterp) {
    const int idx = blockIdx.x * blockDim.x + threadIdx.x;
    if (idx >= PP * LL) return;
    const int p = idx / LL, x = idx % LL;
    const float* hp = havg + (size_t)p * GAVG * 2;
    float re, im;
    if (x < 2) { re = hp[0]; im = hp[1]; }
    else if (x >= LL - 2) { re = hp[(GAVG - 1) * 2]; im = hp[(GAVG - 1) * 2 + 1]; }
    else {
        int j = (x - 2) >> 2;
        float t = ((float)x - (1.5f + 4.0f * (float)j)) * 0.25f;
        float r0 = hp[j * 2],       i0 = hp[j * 2 + 1];
        float r1 = hp[(j + 1) * 2], i1 = hp[(j + 1) * 2 + 1];
        re = r0 + t * (r1 - r0);
        im = i0 + t * (i1 - i0);
    }
    hinterp[idx * 2]     = re;
    hinterp[idx * 2 + 1] = im;
}

// ---------------------------------------------------------------------------
// Kernel 5: residual[l] = ls[l] - sum_p h_interp[p][l] / phasor[p][l]
// ---------------------------------------------------------------------------
__global__ void k_resid(const float* __restrict__ lsr, const float* __restrict__ lsi,
                        const int* __restrict__ peak, const float* __restrict__ hinterp,
                        float* __restrict__ resid) {
    const int l = blockIdx.x * blockDim.x + threadIdx.x;
    if (l >= LL) return;
    const float c0 = (float)(2.0 * M_PI / (double)LL);
    float sr = 0.f, si = 0.f;
    for (int p = 0; p < PP; p++) {
        int m = peak[p];
        int mod = (int)(((long)m * (long)l) % LL);
        float ph = c0 * (float)mod;
        float ss, cc;
        sincosf(ph, &ss, &cc);
        float hr = hinterp[((size_t)p * LL + l) * 2];
        float hi = hinterp[((size_t)p * LL + l) * 2 + 1];
        float den = cc * cc + ss * ss;
        sr += (hr * cc + hi * ss) / den;
        si += (hi * cc - hr * ss) / den;
    }
    resid[l * 2]     = lsr[l] - sr;
    resid[l * 2 + 1] = lsi[l] - si;
}

// ---------------------------------------------------------------------------
// Kernel 6: h_wr = h_interp + residual*phasor; block-MMSE with F; write
//           h_mmse tile 0. CPLX: interleaved re/im. !CPLX: real part only.
// ---------------------------------------------------------------------------
template <bool CPLX>
__global__ void k_mmse(const int* __restrict__ peak, const float* __restrict__ hinterp,
                       const float* __restrict__ resid, const float* __restrict__ F,
                       float* __restrict__ out) {
    const int idx = blockIdx.x * blockDim.x + threadIdx.x;
    if (idx >= PP * NBLK) return;
    const int p = idx / NBLK, b = idx % NBLK;
    const int m = peak[p];
    const float c0 = (float)(2.0 * M_PI / (double)LL);
    float wr[12], wi[12];
    for (int k = 0; k < 12; k++) {
        int n = b * 12 + k;
        int mod = (int)(((long)m * (long)n) % LL);
        float ph = c0 * (float)mod;
        float ss, cc;
        sincosf(ph, &ss, &cc);
        float rr = resid[n * 2], ri = resid[n * 2 + 1];
        wr[k] = hinterp[((size_t)p * LL + n) * 2]     + (rr * cc - ri * ss);
        wi[k] = hinterp[((size_t)p * LL + n) * 2 + 1] + (rr * ss + ri * cc);
    }
    for (int j = 0; j < 12; j++) {
        float ar = 0.f, ai = 0.f;
        for (int k = 0; k < 12; k++) {
            float f = F[j * 12 + k];
            ar += f * wr[k];
            ai += f * wi[k];
        }
        if (CPLX) {
            float* orow = out + (size_t)p * LL * 2 + (size_t)b * 24;
            orow[j * 2]     = ar;
            orow[j * 2 + 1] = ai;
        } else {
            out[(size_t)p * LL + (size_t)b * 12 + j] = ar;
        }
    }
}

// ---------------------------------------------------------------------------
// Kernel 7: tile block 0 to the remaining (P-1) copies (overwrites any
//           scratch living in the output tail; all scratch reads are done).
// ---------------------------------------------------------------------------
__global__ void k_tile(float4* __restrict__ out, int tile_f4) {
    const int idx = blockIdx.x * blockDim.x + threadIdx.x;
    if (idx >= tile_f4) return;
    float4 v = out[idx];
    for (int q = 1; q < PP; q++)
        out[(size_t)q * tile_f4 + idx] = v;
}

extern "C" void kernel_launch(void* const* d_in, const int* in_sizes, int n_in,
                              void* d_out, int out_size, void* d_ws, size_t ws_size,
                              hipStream_t stream) {
    const float* lsr = (const float*)d_in[0];
    const float* lsi = (const float*)d_in[1];
    const int*   cs  = (const int*)d_in[2];
    float* out = (float*)d_out;

    const bool cplx = (out_size >= OUT_CPLX);

    // ---- scratch: prefer d_ws when verifiably big enough, else out tail ----
    float* base;
    if (ws_size >= (size_t)SCRATCH_F * sizeof(float)) {
        base = (float*)d_ws;
    } else {
        base = out + ((size_t)out_size - SCRATCH_F);   // consumed before k_tile
    }
    // layout (float offsets): mag2[672 dbl]=1344f, noise[1 dbl]=2f @1344,
    // peak[32 i32]@2692, F[144 f32]@2724, havg[52224]@2868,
    // hint[208896]@55092, resid[6528]@263988 -> end 270516 (<270520)
    double* mag2  = (double*)base;
    double* noise = mag2 + PP * NW;
    int*    peak  = (int*)(base + 2692);
    float*  F     = base + 2724;
    float*  havg  = base + 2868;
    float*  hint  = base + 55092;
    float*  resid = base + 263988;

    k_window_noise<<<PP * NW + 1, 256, 0, stream>>>(lsr, lsi, cs, mag2, noise);
    k_peak_F<<<1, 192, 0, stream>>>(cs, mag2, noise, peak, F);
    k_havg<<<(PP * GAVG + 255) / 256, 256, 0, stream>>>(lsr, lsi, peak, havg);
    k_interp<<<(PP * LL + 255) / 256, 256, 0, stream>>>(havg, hint);
    k_resid<<<(LL + 255) / 256, 256, 0, stream>>>(lsr, lsi, peak, hint, resid);

    if (cplx) {
        k_mmse<true><<<(PP * NBLK + 255) / 256, 256, 0, stream>>>(peak, hint, resid, F, out);
        const int tile_f4 = PP * LL * 2 / 4;   // 52,224 float4 per tile
        k_tile<<<(tile_f4 + 255) / 256, 256, 0, stream>>>((float4*)out, tile_f4);
    } else {
        k_mmse<false><<<(PP * NBLK + 255) / 256, 256, 0, stream>>>(peak, hint, resid, F, out);
        const int tile_f4 = PP * LL / 4;       // 26,112 float4 per tile
        k_tile<<<(tile_f4 + 255) / 256, 256, 0, stream>>>((float4*)out, tile_f4);
    }
}

// Round 5
// 28.226 us; speedup vs baseline: 12.3075x; 1.9928x over previous
//
#include <hip/hip_runtime.h>
#include <math.h>

#define LL    3264
#define KK    12
#define PP    32           // total ports = 8*4
#define NW    21           // delay search window size (DMAX-DMIN+1)
#define DMIN  (-10)
#define GAVG  (LL/4)       // 816, after OCC averaging (LOCC=4)
#define NBLK  (LL/12)      // 272 MMSE blocks

#define OUT_REAL  (PP*PP*LL)      // 3,342,336  (harness compares real part, fp32)
#define OUT_CPLX  (PP*PP*LL*2)    // 6,684,672  (interleaved re/im)
#define SCRATCH_F 270520          // floats of scratch for the FALLBACK path

// ---------------------------------------------------------------------------
// Kernel 1: per-(port,window-pos) direct DFT |.|^2. Angles in fp32 (sincosf,
//           ~10x cheaper than double sincos; n*t < 2^24 so int32 mod exact),
//           accumulation in double. Last block: noise power.
// ---------------------------------------------------------------------------
__global__ void k_window_noise(const float* __restrict__ lsr,
                               const float* __restrict__ lsi,
                               const int* __restrict__ cs,
                               double* __restrict__ mag2,
                               double* __restrict__ noise) {
    __shared__ double sre[256], sim[256];
    const int b = blockIdx.x;
    const int tid = threadIdx.x;
    const float c0 = (float)(2.0 * M_PI / (double)LL);
    if (b < PP * NW) {
        const int p = b / NW, r = b % NW;
        const int ideal = ((KK - cs[p]) % KK) * (LL / KK);
        int t = ideal + DMIN + r;
        t %= LL; if (t < 0) t += LL;
        double are = 0.0, aim = 0.0;
        for (int n = tid; n < LL; n += 256) {
            unsigned mod = (unsigned)(n * t) % LL;       // n*t < 3264^2 < 2^24
            float ang = c0 * (float)mod;
            float ss, cc;
            sincosf(ang, &ss, &cc);
            float xr = lsr[n], xi = lsi[n];
            are += (double)(xr * cc - xi * ss);          // ls[n]*exp(+i ang)
            aim += (double)(xr * ss + xi * cc);
        }
        sre[tid] = are; sim[tid] = aim;
        __syncthreads();
        for (int s = 128; s > 0; s >>= 1) {
            if (tid < s) { sre[tid] += sre[tid + s]; sim[tid] += sim[tid + s]; }
            __syncthreads();
        }
        if (tid == 0) mag2[b] = sre[0] * sre[0] + sim[0] * sim[0];
    } else {
        double acc = 0.0;
        for (int n = tid; n < LL - 1; n += 256) {
            double dr = (double)lsr[n + 1] - (double)lsr[n];
            double di = (double)lsi[n + 1] - (double)lsi[n];
            acc += dr * dr + di * di;
        }
        sre[tid] = acc;
        __syncthreads();
        for (int s = 128; s > 0; s >>= 1) {
            if (tid < s) sre[tid] += sre[tid + s];
            __syncthreads();
        }
        if (tid == 0) *noise = sre[0] / (double)(LL - 1) * 0.5;
    }
}

// ---------------------------------------------------------------------------
// Kernel 2: per-port argmax (threads 0..31) + parallel 12x12 Gauss-Jordan in
//           shared memory (threads 0..143): F = C*inv(A). A SPD -> no pivot.
// ---------------------------------------------------------------------------
__global__ void k_peak_F(const int* __restrict__ cs,
                         const double* __restrict__ mag2,
                         const double* __restrict__ noise,
                         int* __restrict__ peak,
                         float* __restrict__ F) {
    __shared__ double A[12][12], Y[12][12];
    const int tid = threadIdx.x;

    if (tid < PP) {
        const int ideal = ((KK - cs[tid]) % KK) * (LL / KK);
        double best = -1.0; int bestl = 0x7fffffff;
        for (int r = 0; r < NW; r++) {
            int l = ideal + DMIN + r;
            l %= LL; if (l < 0) l += LL;
            double v = mag2[tid * NW + r];
            if (v > best || (v == best && l < bestl)) { best = v; bestl = l; }
        }
        peak[tid] = bestl;
    }

    const int row = tid / 12, c = tid % 12;
    if (tid < 144) {
        int d = row - c; if (d < 0) d = -d;
        float cij = (float)pow(0.9, (double)d);          // C is fp32 in reference
        double npow = (double)((float)(*noise));         // reference noise is fp32
        A[row][c] = (double)cij + (row == c ? npow : 0.0);
        Y[row][c] = (double)cij;                         // solve A*Y = C
    }
    __syncthreads();

    for (int col = 0; col < 12; col++) {
        double dinv = 0.0, pa = 0.0, py = 0.0, f = 0.0;
        if (tid < 144) {
            dinv = 1.0 / A[col][col];
            pa = A[col][c]; py = Y[col][c];
            f  = A[row][col];
        }
        __syncthreads();
        if (tid < 144) {
            if (row == col) { A[row][c] = pa * dinv; Y[row][c] = py * dinv; }
            else            { A[row][c] -= (f * dinv) * pa; Y[row][c] -= (f * dinv) * py; }
        }
        __syncthreads();
    }
    if (tid < 144) F[row * 12 + c] = (float)Y[c][row];   // F[j][k] = Y[k][j]
}

// ---------------------------------------------------------------------------
// Kernel 3 (FUSED): one block per 12-sample position block b. Everything is
// position-local: havg[j] needs 8 ls values; interp at x needs havg[j..j+1]
// with j in [3b-1, 3b+3]; resid/mmse need only this block's positions.
// Computes havg -> hint -> resid -> h_wr -> MMSE and writes all 32 tile
// copies directly (no intermediate global traffic, no separate tile pass).
// ---------------------------------------------------------------------------
template <bool CPLX>
__global__ __launch_bounds__(384) void k_fused(const float* __restrict__ lsr,
                                               const float* __restrict__ lsi,
                                               const int* __restrict__ peak,
                                               const float* __restrict__ F,
                                               float* __restrict__ out) {
    const int b = blockIdx.x;        // 0..271
    const int tid = threadIdx.x;     // 384
    __shared__ float hav[32][5][2];  // havg slots jbase..jbase+4
    __shared__ float hin[32][12][2];
    __shared__ float pha[32][12][2];
    __shared__ float con[32][12][2]; // per-port resid contributions
    __shared__ float w_s[32][12][2]; // h_wr
    __shared__ float res[12][2];
    __shared__ float Fs[144];
    __shared__ int   pk[32];

    if (tid < 144) Fs[tid] = F[tid];
    if (tid < 32)  pk[tid] = peak[tid];
    __syncthreads();

    const int jb3 = 3 * b - 1;
    const int jbase = jb3 < 0 ? 0 : jb3;
    const float c0 = (float)(2.0 * M_PI / (double)LL);

    // phase 1: havg for 5 j-slots x 32 ports
    if (tid < 160) {
        const int p = tid / 5, js = tid % 5;
        int j = jbase + js; if (j > GAVG - 1) j = GAVG - 1;
        const int m = pk[p];
        float ar = 0.f, ai = 0.f;
        for (int s = 0; s < 4; s++) {
            int n = j * 4 + s;
            unsigned mod = (unsigned)(m * n) % LL;       // m*n < 2^24
            float ang = c0 * (float)mod;
            float ss, cc;
            sincosf(ang, &ss, &cc);
            float xr = lsr[n], xi = lsi[n];
            ar += xr * cc - xi * ss;
            ai += xr * ss + xi * cc;
        }
        hav[p][js][0] = ar * 0.25f;
        hav[p][js][1] = ai * 0.25f;
    }
    __syncthreads();

    // phase 2: hint (linear interp), phasor, resid contributions
    {
        const int p = tid / 12, k = tid % 12;
        const int x = b * 12 + k;
        float re, im;
        if (x < 2)            { re = hav[p][0][0]; im = hav[p][0][1]; }
        else if (x >= LL - 2) { int js = (GAVG - 1) - jbase;            // b==271 only
                                re = hav[p][js][0]; im = hav[p][js][1]; }
        else {
            int j = (x - 2) >> 2, js = j - jbase;
            float t = ((float)x - (1.5f + 4.0f * (float)j)) * 0.25f;
            float r0 = hav[p][js][0],     i0 = hav[p][js][1];
            float r1 = hav[p][js + 1][0], i1 = hav[p][js + 1][1];
            re = r0 + t * (r1 - r0);
            im = i0 + t * (i1 - i0);
        }
        hin[p][k][0] = re; hin[p][k][1] = im;
        const int m = pk[p];
        unsigned mod = (unsigned)(m * x) % LL;
        float ang = c0 * (float)mod;
        float ss, cc;
        sincosf(ang, &ss, &cc);
        pha[p][k][0] = cc; pha[p][k][1] = ss;
        float den = cc * cc + ss * ss;
        con[p][k][0] = (re * cc + im * ss) / den;        // h_interp / phasor
        con[p][k][1] = (im * cc - re * ss) / den;
    }
    __syncthreads();

    // phase 3: resid[k] = ls - sum_p contrib  (same p-order as reference path)
    if (tid < 24) {
        const int k = tid >> 1, c = tid & 1;
        float s = 0.f;
        for (int p = 0; p < 32; p++) s += con[p][k][c];
        const int n = b * 12 + k;
        res[k][c] = (c ? lsi[n] : lsr[n]) - s;
    }
    __syncthreads();

    // phase 4: h_wr = hint + resid * phasor
    {
        const int p = tid / 12, k = tid % 12;
        float rr = res[k][0], ri = res[k][1];
        float cc = pha[p][k][0], ss = pha[p][k][1];
        w_s[p][k][0] = hin[p][k][0] + rr * cc - ri * ss;
        w_s[p][k][1] = hin[p][k][1] + rr * ss + ri * cc;
    }
    __syncthreads();

    // phase 5: MMSE (12x12 dot) + broadcast to all 32 tile copies
    {
        const int p = tid / 12, j = tid % 12;
        float ar = 0.f, ai = 0.f;
        for (int k = 0; k < 12; k++) {
            float f = Fs[j * 12 + k];
            ar += f * w_s[p][k][0];
            ai += f * w_s[p][k][1];
        }
        if (CPLX) {
            const size_t off = ((size_t)p * LL + (size_t)b * 12 + j) * 2;
            for (int q = 0; q < PP; q++) {
                out[(size_t)q * PP * LL * 2 + off]     = ar;
                out[(size_t)q * PP * LL * 2 + off + 1] = ai;
            }
        } else {
            const size_t off = (size_t)p * LL + (size_t)b * 12 + j;
            for (int q = 0; q < PP; q++)
                out[(size_t)q * PP * LL + off] = ar;
        }
    }
}

// ===========================================================================
// FALLBACK path (proven in R3/R4): used only if d_ws is too small; scratch
// then lives in the d_out tail, consumed before the final tile pass.
// ===========================================================================
__global__ void k_havg(const float* __restrict__ lsr, const float* __restrict__ lsi,
                       const int* __restrict__ peak, float* __restrict__ havg) {
    const int idx = blockIdx.x * blockDim.x + threadIdx.x;
    if (idx >= PP * GAVG) return;
    const int p = idx / GAVG, jj = idx % GAVG;
    const int m = peak[p];
    const float c0 = (float)(2.0 * M_PI / (double)LL);
    float ar = 0.f, ai = 0.f;
    for (int s = 0; s < 4; s++) {
        int n = jj * 4 + s;
        unsigned mod = (unsigned)(m * n) % LL;
        float ph = c0 * (float)mod;
        float ss, cc;
        sincosf(ph, &ss, &cc);
        float xr = lsr[n], xi = lsi[n];
        ar += xr * cc - xi * ss;
        ai += xr * ss + xi * cc;
    }
    havg[idx * 2]     = ar * 0.25f;
    havg[idx * 2 + 1] = ai * 0.25f;
}

__global__ void k_interp(const float* __restrict__ havg, float* __restrict__ hinterp) {
    const int idx = blockIdx.x * blockDim.x + threadIdx.x;
    if (idx >= PP * LL) return;
    const int p = idx / LL, x = idx % LL;
    const float* hp = havg + (size_t)p * GAVG * 2;
    float re, im;
    if (x < 2) { re = hp[0]; im = hp[1]; }
    else if (x >= LL - 2) { re = hp[(GAVG - 1) * 2]; im = hp[(GAVG - 1) * 2 + 1]; }
    else {
        int j = (x - 2) >> 2;
        float t = ((float)x - (1.5f + 4.0f * (float)j)) * 0.25f;
        float r0 = hp[j * 2],       i0 = hp[j * 2 + 1];
        float r1 = hp[(j + 1) * 2], i1 = hp[(j + 1) * 2 + 1];
        re = r0 + t * (r1 - r0);
        im = i0 + t * (i1 - i0);
    }
    hinterp[idx * 2]     = re;
    hinterp[idx * 2 + 1] = im;
}

__global__ void k_resid(const float* __restrict__ lsr, const float* __restrict__ lsi,
                        const int* __restrict__ peak, const float* __restrict__ hinterp,
                        float* __restrict__ resid) {
    const int l = blockIdx.x * blockDim.x + threadIdx.x;
    if (l >= LL) return;
    const float c0 = (float)(2.0 * M_PI / (double)LL);
    float sr = 0.f, si = 0.f;
    for (int p = 0; p < PP; p++) {
        int m = peak[p];
        unsigned mod = (unsigned)(m * l) % LL;
        float ph = c0 * (float)mod;
        float ss, cc;
        sincosf(ph, &ss, &cc);
        float hr = hinterp[((size_t)p * LL + l) * 2];
        float hi = hinterp[((size_t)p * LL + l) * 2 + 1];
        float den = cc * cc + ss * ss;
        sr += (hr * cc + hi * ss) / den;
        si += (hi * cc - hr * ss) / den;
    }
    resid[l * 2]     = lsr[l] - sr;
    resid[l * 2 + 1] = lsi[l] - si;
}

template <bool CPLX>
__global__ void k_mmse(const int* __restrict__ peak, const float* __restrict__ hinterp,
                       const float* __restrict__ resid, const float* __restrict__ F,
                       float* __restrict__ out) {
    const int idx = blockIdx.x * blockDim.x + threadIdx.x;
    if (idx >= PP * NBLK) return;
    const int p = idx / NBLK, b = idx % NBLK;
    const int m = peak[p];
    const float c0 = (float)(2.0 * M_PI / (double)LL);
    float wr[12], wi[12];
    for (int k = 0; k < 12; k++) {
        int n = b * 12 + k;
        unsigned mod = (unsigned)(m * n) % LL;
        float ph = c0 * (float)mod;
        float ss, cc;
        sincosf(ph, &ss, &cc);
        float rr = resid[n * 2], ri = resid[n * 2 + 1];
        wr[k] = hinterp[((size_t)p * LL + n) * 2]     + (rr * cc - ri * ss);
        wi[k] = hinterp[((size_t)p * LL + n) * 2 + 1] + (rr * ss + ri * cc);
    }
    for (int j = 0; j < 12; j++) {
        float ar = 0.f, ai = 0.f;
        for (int k = 0; k < 12; k++) {
            float f = F[j * 12 + k];
            ar += f * wr[k];
            ai += f * wi[k];
        }
        if (CPLX) {
            float* orow = out + (size_t)p * LL * 2 + (size_t)b * 24;
            orow[j * 2]     = ar;
            orow[j * 2 + 1] = ai;
        } else {
            out[(size_t)p * LL + (size_t)b * 12 + j] = ar;
        }
    }
}

__global__ void k_tile(float4* __restrict__ out, int tile_f4) {
    const int idx = blockIdx.x * blockDim.x + threadIdx.x;
    if (idx >= tile_f4) return;
    float4 v = out[idx];
    for (int q = 1; q < PP; q++)
        out[(size_t)q * tile_f4 + idx] = v;
}

extern "C" void kernel_launch(void* const* d_in, const int* in_sizes, int n_in,
                              void* d_out, int out_size, void* d_ws, size_t ws_size,
                              hipStream_t stream) {
    const float* lsr = (const float*)d_in[0];
    const float* lsi = (const float*)d_in[1];
    const int*   cs  = (const int*)d_in[2];
    float* out = (float*)d_out;
    const bool cplx = (out_size >= OUT_CPLX);

    if (ws_size >= 16384) {
        // FAST PATH: small scratch in d_ws (mag2 672 dbl + noise + peak + F)
        double* mag2  = (double*)d_ws;
        double* noise = mag2 + PP * NW;
        int*    peak  = (int*)(noise + 1);
        float*  F     = (float*)(peak + PP);

        k_window_noise<<<PP * NW + 1, 256, 0, stream>>>(lsr, lsi, cs, mag2, noise);
        k_peak_F<<<1, 192, 0, stream>>>(cs, mag2, noise, peak, F);
        if (cplx) k_fused<true ><<<NBLK, 384, 0, stream>>>(lsr, lsi, peak, F, out);
        else      k_fused<false><<<NBLK, 384, 0, stream>>>(lsr, lsi, peak, F, out);
    } else {
        // FALLBACK (R4-proven): scratch in the tail of d_out
        float* base = out + ((size_t)out_size - SCRATCH_F);
        double* mag2  = (double*)base;
        double* noise = mag2 + PP * NW;
        int*    peak  = (int*)(base + 2692);
        float*  F     = base + 2724;
        float*  havg  = base + 2868;
        float*  hint  = base + 55092;
        float*  resid = base + 263988;

        k_window_noise<<<PP * NW + 1, 256, 0, stream>>>(lsr, lsi, cs, mag2, noise);
        k_peak_F<<<1, 192, 0, stream>>>(cs, mag2, noise, peak, F);
        k_havg<<<(PP * GAVG + 255) / 256, 256, 0, stream>>>(lsr, lsi, peak, havg);
        k_interp<<<(PP * LL + 255) / 256, 256, 0, stream>>>(havg, hint);
        k_resid<<<(LL + 255) / 256, 256, 0, stream>>>(lsr, lsi, peak, hint, resid);
        if (cplx) {
            k_mmse<true><<<(PP * NBLK + 255) / 256, 256, 0, stream>>>(peak, hint, resid, F, out);
            const int tile_f4 = PP * LL * 2 / 4;
            k_tile<<<(tile_f4 + 255) / 256, 256, 0, stream>>>((float4*)out, tile_f4);
        } else {
            k_mmse<false><<<(PP * NBLK + 255) / 256, 256, 0, stream>>>(peak, hint, resid, F, out);
            const int tile_f4 = PP * LL / 4;
            k_tile<<<(tile_f4 + 255) / 256, 256, 0, stream>>>((float4*)out, tile_f4);
        }
    }
}

// Round 6
// 26.498 us; speedup vs baseline: 13.1099x; 1.0652x over previous
//
#include <hip/hip_runtime.h>
#include <math.h>

#define LL    3264
#define KK    12
#define PP    32           // total ports = 8*4
#define NW    21           // delay search window size (DMAX-DMIN+1)
#define DMIN  (-10)
#define GAVG  (LL/4)       // 816, after OCC averaging (LOCC=4)
#define NBLK  (LL/12)      // 272 MMSE blocks
#define NIDE  12           // distinct ideal positions: ((12-cs)%12)*272
#define NMAG  (NIDE*NW)    // 252 distinct window DFTs

#define OUT_REAL  (PP*PP*LL)      // 3,342,336  (harness compares real fp32)
#define OUT_CPLX  (PP*PP*LL*2)    // 6,684,672  (interleaved re/im)
#define SCRATCH_F 270520          // floats of scratch for the FALLBACK path

// ---------------------------------------------------------------------------
// Kernel 1: blocks 0..251 compute one distinct window-position DFT |.|^2
// (dedup: only 12 distinct ideals x 21 offsets exist). Block 252 computes
// noise power AND the 12x12 MMSE filter F = C*inv(A) (F depends only on
// noise, so no extra kernel needed). fp32 sincosf, double accumulation.
// ---------------------------------------------------------------------------
__global__ void k_win_noise_F(const float* __restrict__ lsr,
                              const float* __restrict__ lsi,
                              double* __restrict__ mag2,
                              float* __restrict__ F) {
    __shared__ double sre[256], sim[256];
    const int b = blockIdx.x;
    const int tid = threadIdx.x;
    const float c0 = (float)(2.0 * M_PI / (double)LL);
    if (b < NMAG) {
        const int i = b / NW, r = b % NW;
        int t = i * (LL / KK) + DMIN + r;
        t %= LL; if (t < 0) t += LL;
        double are = 0.0, aim = 0.0;
        for (int n = tid; n < LL; n += 256) {
            unsigned mod = (unsigned)(n * t) % LL;       // n*t < 2^24, exact
            float ang = c0 * (float)mod;
            float ss, cc;
            sincosf(ang, &ss, &cc);
            float xr = lsr[n], xi = lsi[n];
            are += (double)(xr * cc - xi * ss);          // ls[n]*exp(+i ang)
            aim += (double)(xr * ss + xi * cc);
        }
        sre[tid] = are; sim[tid] = aim;
        __syncthreads();
        for (int s = 128; s > 0; s >>= 1) {
            if (tid < s) { sre[tid] += sre[tid + s]; sim[tid] += sim[tid + s]; }
            __syncthreads();
        }
        if (tid == 0) mag2[b] = sre[0] * sre[0] + sim[0] * sim[0];
    } else {
        // ---- noise power ----
        double acc = 0.0;
        for (int n = tid; n < LL - 1; n += 256) {
            double dr = (double)lsr[n + 1] - (double)lsr[n];
            double di = (double)lsi[n + 1] - (double)lsi[n];
            acc += dr * dr + di * di;
        }
        sre[tid] = acc;
        __syncthreads();
        for (int s = 128; s > 0; s >>= 1) {
            if (tid < s) sre[tid] += sre[tid + s];
            __syncthreads();
        }
        if (tid == 0) sre[0] = (double)((float)(sre[0] / (double)(LL - 1) * 0.5));
        __syncthreads();
        const double npow = sre[0];                      // fp32-rounded, as ref

        // ---- F = C*inv(A), parallel Gauss-Jordan (A SPD, no pivot) ----
        __shared__ double A[12][12], Y[12][12];
        const int row = tid / 12, c = tid % 12;
        if (tid < 144) {
            int d = row - c; if (d < 0) d = -d;
            float cij = (float)pow(0.9, (double)d);      // C is fp32 in ref
            A[row][c] = (double)cij + (row == c ? npow : 0.0);
            Y[row][c] = (double)cij;                     // solve A*Y = C
        }
        __syncthreads();
        for (int col = 0; col < 12; col++) {
            double dinv = 0.0, pa = 0.0, py = 0.0, f = 0.0;
            if (tid < 144) {
                dinv = 1.0 / A[col][col];
                pa = A[col][c]; py = Y[col][c];
                f  = A[row][col];
            }
            __syncthreads();
            if (tid < 144) {
                if (row == col) { A[row][c] = pa * dinv; Y[row][c] = py * dinv; }
                else            { A[row][c] -= (f * dinv) * pa; Y[row][c] -= (f * dinv) * py; }
            }
            __syncthreads();
        }
        if (tid < 144) F[row * 12 + c] = (float)Y[c][row];   // F[j][k]=Y[k][j]
    }
}

// ---------------------------------------------------------------------------
// Kernel 2 (FUSED): one block per 12-sample position block b. Starts by
// computing per-port argmax (threads 0..31, L2-hot mag2 reads), then
// havg -> hint -> resid -> h_wr -> MMSE, then float4-broadcasts to all 32
// tile copies. No global intermediates.
// ---------------------------------------------------------------------------
template <bool CPLX>
__global__ __launch_bounds__(384) void k_fused(const float* __restrict__ lsr,
                                               const float* __restrict__ lsi,
                                               const int* __restrict__ cs,
                                               const double* __restrict__ mag2,
                                               const float* __restrict__ Fg,
                                               float* __restrict__ out) {
    const int b = blockIdx.x;        // 0..271
    const int tid = threadIdx.x;     // 384
    __shared__ float hav[32][5][2];  // havg slots jbase..jbase+4
    __shared__ float hin[32][12][2];
    __shared__ float pha[32][12][2];
    __shared__ float con[32][12][2]; // per-port resid contributions
    __shared__ float w_s[32][12][2]; // h_wr
    __shared__ float res[12][2];
    __shared__ float Fs[144];
    __shared__ int   pk[32];
    __shared__ __align__(16) float smo[768];

    if (tid < 144) Fs[tid] = Fg[tid];
    if (tid < 32) {                  // per-port argmax (first-max by abs idx l)
        const int idl = (KK - cs[tid]) % KK;
        const int ideal = idl * (LL / KK);
        double best = -1.0; int bestl = 0x7fffffff;
        for (int r = 0; r < NW; r++) {
            int l = ideal + DMIN + r;
            l %= LL; if (l < 0) l += LL;
            double v = mag2[idl * NW + r];
            if (v > best || (v == best && l < bestl)) { best = v; bestl = l; }
        }
        pk[tid] = bestl;
    }
    __syncthreads();

    const int jb3 = 3 * b - 1;
    const int jbase = jb3 < 0 ? 0 : jb3;
    const float c0 = (float)(2.0 * M_PI / (double)LL);

    // phase 1: havg for 5 j-slots x 32 ports
    if (tid < 160) {
        const int p = tid / 5, js = tid % 5;
        int j = jbase + js; if (j > GAVG - 1) j = GAVG - 1;
        const int m = pk[p];
        float ar = 0.f, ai = 0.f;
        for (int s = 0; s < 4; s++) {
            int n = j * 4 + s;
            unsigned mod = (unsigned)(m * n) % LL;       // m*n < 2^24
            float ang = c0 * (float)mod;
            float ss, cc;
            sincosf(ang, &ss, &cc);
            float xr = lsr[n], xi = lsi[n];
            ar += xr * cc - xi * ss;
            ai += xr * ss + xi * cc;
        }
        hav[p][js][0] = ar * 0.25f;
        hav[p][js][1] = ai * 0.25f;
    }
    __syncthreads();

    // phase 2: hint (linear interp), phasor, resid contributions
    {
        const int p = tid / 12, k = tid % 12;
        const int x = b * 12 + k;
        float re, im;
        if (x < 2)            { re = hav[p][0][0]; im = hav[p][0][1]; }
        else if (x >= LL - 2) { int js = (GAVG - 1) - jbase;            // b==271
                                re = hav[p][js][0]; im = hav[p][js][1]; }
        else {
            int j = (x - 2) >> 2, js = j - jbase;
            float t = ((float)x - (1.5f + 4.0f * (float)j)) * 0.25f;
            float r0 = hav[p][js][0],     i0 = hav[p][js][1];
            float r1 = hav[p][js + 1][0], i1 = hav[p][js + 1][1];
            re = r0 + t * (r1 - r0);
            im = i0 + t * (i1 - i0);
        }
        hin[p][k][0] = re; hin[p][k][1] = im;
        const int m = pk[p];
        unsigned mod = (unsigned)(m * x) % LL;
        float ang = c0 * (float)mod;
        float ss, cc;
        sincosf(ang, &ss, &cc);
        pha[p][k][0] = cc; pha[p][k][1] = ss;
        float den = cc * cc + ss * ss;
        con[p][k][0] = (re * cc + im * ss) / den;        // h_interp / phasor
        con[p][k][1] = (im * cc - re * ss) / den;
    }
    __syncthreads();

    // phase 3: resid[k] = ls - sum_p contrib
    if (tid < 24) {
        const int k = tid >> 1, c = tid & 1;
        float s = 0.f;
        for (int p = 0; p < 32; p++) s += con[p][k][c];
        const int n = b * 12 + k;
        res[k][c] = (c ? lsi[n] : lsr[n]) - s;
    }
    __syncthreads();

    // phase 4: h_wr = hint + resid * phasor
    {
        const int p = tid / 12, k = tid % 12;
        float rr = res[k][0], ri = res[k][1];
        float cc = pha[p][k][0], ss = pha[p][k][1];
        w_s[p][k][0] = hin[p][k][0] + rr * cc - ri * ss;
        w_s[p][k][1] = hin[p][k][1] + rr * ss + ri * cc;
    }
    __syncthreads();

    // phase 5: MMSE (12x12 dot) into LDS staging
    {
        const int p = tid / 12, j = tid % 12;
        float ar = 0.f, ai = 0.f;
        for (int k = 0; k < 12; k++) {
            float f = Fs[j * 12 + k];
            ar += f * w_s[p][k][0];
            ai += f * w_s[p][k][1];
        }
        if (CPLX) { smo[(p * 12 + j) * 2] = ar; smo[(p * 12 + j) * 2 + 1] = ai; }
        else      { smo[p * 12 + j] = ar; }
    }
    __syncthreads();

    // phase 6: float4 broadcast to all 32 tile copies
    const float4* smo4 = (const float4*)smo;
    float4* out4 = (float4*)out;
    if (CPLX) {
        // per q-copy: 32 ports x 6 float4; addr4 = q*52224 + p*1632 + b*6 + w
        for (int idx = tid; idx < 32 * 192; idx += 384) {
            const int q = idx / 192, c = idx % 192;
            const int p = c / 6, w = c % 6;
            out4[(size_t)q * (PP * LL * 2 / 4) + p * (LL / 2) + b * 6 + w] = smo4[c];
        }
    } else {
        // per q-copy: 32 ports x 3 float4; addr4 = q*26112 + p*816 + b*3 + w
        for (int idx = tid; idx < 32 * 96; idx += 384) {
            const int q = idx / 96, c = idx % 96;
            const int p = c / 3, w = c % 3;
            out4[(size_t)q * (PP * LL / 4) + p * (LL / 4) + b * 3 + w] = smo4[c];
        }
    }
}

// ===========================================================================
// FALLBACK path (R5-proven): only if d_ws is too small; scratch in d_out
// tail, consumed before the final tile pass.
// ===========================================================================
__global__ void k_window_noise_fb(const float* __restrict__ lsr,
                                  const float* __restrict__ lsi,
                                  const int* __restrict__ cs,
                                  double* __restrict__ mag2,
                                  double* __restrict__ noise) {
    __shared__ double sre[256], sim[256];
    const int b = blockIdx.x;
    const int tid = threadIdx.x;
    const float c0 = (float)(2.0 * M_PI / (double)LL);
    if (b < PP * NW) {
        const int p = b / NW, r = b % NW;
        const int ideal = ((KK - cs[p]) % KK) * (LL / KK);
        int t = ideal + DMIN + r;
        t %= LL; if (t < 0) t += LL;
        double are = 0.0, aim = 0.0;
        for (int n = tid; n < LL; n += 256) {
            unsigned mod = (unsigned)(n * t) % LL;
            float ang = c0 * (float)mod;
            float ss, cc;
            sincosf(ang, &ss, &cc);
            float xr = lsr[n], xi = lsi[n];
            are += (double)(xr * cc - xi * ss);
            aim += (double)(xr * ss + xi * cc);
        }
        sre[tid] = are; sim[tid] = aim;
        __syncthreads();
        for (int s = 128; s > 0; s >>= 1) {
            if (tid < s) { sre[tid] += sre[tid + s]; sim[tid] += sim[tid + s]; }
            __syncthreads();
        }
        if (tid == 0) mag2[b] = sre[0] * sre[0] + sim[0] * sim[0];
    } else {
        double acc = 0.0;
        for (int n = tid; n < LL - 1; n += 256) {
            double dr = (double)lsr[n + 1] - (double)lsr[n];
            double di = (double)lsi[n + 1] - (double)lsi[n];
            acc += dr * dr + di * di;
        }
        sre[tid] = acc;
        __syncthreads();
        for (int s = 128; s > 0; s >>= 1) {
            if (tid < s) sre[tid] += sre[tid + s];
            __syncthreads();
        }
        if (tid == 0) *noise = sre[0] / (double)(LL - 1) * 0.5;
    }
}

__global__ void k_peak_F_fb(const int* __restrict__ cs,
                            const double* __restrict__ mag2,
                            const double* __restrict__ noise,
                            int* __restrict__ peak,
                            float* __restrict__ F) {
    __shared__ double A[12][12], Y[12][12];
    const int tid = threadIdx.x;
    if (tid < PP) {
        const int ideal = ((KK - cs[tid]) % KK) * (LL / KK);
        double best = -1.0; int bestl = 0x7fffffff;
        for (int r = 0; r < NW; r++) {
            int l = ideal + DMIN + r;
            l %= LL; if (l < 0) l += LL;
            double v = mag2[tid * NW + r];
            if (v > best || (v == best && l < bestl)) { best = v; bestl = l; }
        }
        peak[tid] = bestl;
    }
    const int row = tid / 12, c = tid % 12;
    if (tid < 144) {
        int d = row - c; if (d < 0) d = -d;
        float cij = (float)pow(0.9, (double)d);
        double npow = (double)((float)(*noise));
        A[row][c] = (double)cij + (row == c ? npow : 0.0);
        Y[row][c] = (double)cij;
    }
    __syncthreads();
    for (int col = 0; col < 12; col++) {
        double dinv = 0.0, pa = 0.0, py = 0.0, f = 0.0;
        if (tid < 144) {
            dinv = 1.0 / A[col][col];
            pa = A[col][c]; py = Y[col][c];
            f  = A[row][col];
        }
        __syncthreads();
        if (tid < 144) {
            if (row == col) { A[row][c] = pa * dinv; Y[row][c] = py * dinv; }
            else            { A[row][c] -= (f * dinv) * pa; Y[row][c] -= (f * dinv) * py; }
        }
        __syncthreads();
    }
    if (tid < 144) F[row * 12 + c] = (float)Y[c][row];
}

__global__ void k_havg(const float* __restrict__ lsr, const float* __restrict__ lsi,
                       const int* __restrict__ peak, float* __restrict__ havg) {
    const int idx = blockIdx.x * blockDim.x + threadIdx.x;
    if (idx >= PP * GAVG) return;
    const int p = idx / GAVG, jj = idx % GAVG;
    const int m = peak[p];
    const float c0 = (float)(2.0 * M_PI / (double)LL);
    float ar = 0.f, ai = 0.f;
    for (int s = 0; s < 4; s++) {
        int n = jj * 4 + s;
        unsigned mod = (unsigned)(m * n) % LL;
        float ph = c0 * (float)mod;
        float ss, cc;
        sincosf(ph, &ss, &cc);
        float xr = lsr[n], xi = lsi[n];
        ar += xr * cc - xi * ss;
        ai += xr * ss + xi * cc;
    }
    havg[idx * 2]     = ar * 0.25f;
    havg[idx * 2 + 1] = ai * 0.25f;
}

__global__ void k_interp(const float* __restrict__ havg, float* __restrict__ hinterp) {
    const int idx = blockIdx.x * blockDim.x + threadIdx.x;
    if (idx >= PP * LL) return;
    const int p = idx / LL, x = idx % LL;
    const float* hp = havg + (size_t)p * GAVG * 2;
    float re, im;
    if (x < 2) { re = hp[0]; im = hp[1]; }
    else if (x >= LL - 2) { re = hp[(GAVG - 1) * 2]; im = hp[(GAVG - 1) * 2 + 1]; }
    else {
        int j = (x - 2) >> 2;
        float t = ((float)x - (1.5f + 4.0f * (float)j)) * 0.25f;
        float r0 = hp[j * 2],       i0 = hp[j * 2 + 1];
        float r1 = hp[(j + 1) * 2], i1 = hp[(j + 1) * 2 + 1];
        re = r0 + t * (r1 - r0);
        im = i0 + t * (i1 - i0);
    }
    hinterp[idx * 2]     = re;
    hinterp[idx * 2 + 1] = im;
}

__global__ void k_resid(const float* __restrict__ lsr, const float* __restrict__ lsi,
                        const int* __restrict__ peak, const float* __restrict__ hinterp,
                        float* __restrict__ resid) {
    const int l = blockIdx.x * blockDim.x + threadIdx.x;
    if (l >= LL) return;
    const float c0 = (float)(2.0 * M_PI / (double)LL);
    float sr = 0.f, si = 0.f;
    for (int p = 0; p < PP; p++) {
        int m = peak[p];
        unsigned mod = (unsigned)(m * l) % LL;
        float ph = c0 * (float)mod;
        float ss, cc;
        sincosf(ph, &ss, &cc);
        float hr = hinterp[((size_t)p * LL + l) * 2];
        float hi = hinterp[((size_t)p * LL + l) * 2 + 1];
        float den = cc * cc + ss * ss;
        sr += (hr * cc + hi * ss) / den;
        si += (hi * cc - hr * ss) / den;
    }
    resid[l * 2]     = lsr[l] - sr;
    resid[l * 2 + 1] = lsi[l] - si;
}

template <bool CPLX>
__global__ void k_mmse(const int* __restrict__ peak, const float* __restrict__ hinterp,
                       const float* __restrict__ resid, const float* __restrict__ F,
                       float* __restrict__ out) {
    const int idx = blockIdx.x * blockDim.x + threadIdx.x;
    if (idx >= PP * NBLK) return;
    const int p = idx / NBLK, b = idx % NBLK;
    const int m = peak[p];
    const float c0 = (float)(2.0 * M_PI / (double)LL);
    float wr[12], wi[12];
    for (int k = 0; k < 12; k++) {
        int n = b * 12 + k;
        unsigned mod = (unsigned)(m * n) % LL;
        float ph = c0 * (float)mod;
        float ss, cc;
        sincosf(ph, &ss, &cc);
        float rr = resid[n * 2], ri = resid[n * 2 + 1];
        wr[k] = hinterp[((size_t)p * LL + n) * 2]     + (rr * cc - ri * ss);
        wi[k] = hinterp[((size_t)p * LL + n) * 2 + 1] + (rr * ss + ri * cc);
    }
    for (int j = 0; j < 12; j++) {
        float ar = 0.f, ai = 0.f;
        for (int k = 0; k < 12; k++) {
            float f = F[j * 12 + k];
            ar += f * wr[k];
            ai += f * wi[k];
        }
        if (CPLX) {
            float* orow = out + (size_t)p * LL * 2 + (size_t)b * 24;
            orow[j * 2]     = ar;
            orow[j * 2 + 1] = ai;
        } else {
            out[(size_t)p * LL + (size_t)b * 12 + j] = ar;
        }
    }
}

__global__ void k_tile(float4* __restrict__ out, int tile_f4) {
    const int idx = blockIdx.x * blockDim.x + threadIdx.x;
    if (idx >= tile_f4) return;
    float4 v = out[idx];
    for (int q = 1; q < PP; q++)
        out[(size_t)q * tile_f4 + idx] = v;
}

extern "C" void kernel_launch(void* const* d_in, const int* in_sizes, int n_in,
                              void* d_out, int out_size, void* d_ws, size_t ws_size,
                              hipStream_t stream) {
    const float* lsr = (const float*)d_in[0];
    const float* lsi = (const float*)d_in[1];
    const int*   cs  = (const int*)d_in[2];
    float* out = (float*)d_out;
    const bool cplx = (out_size >= OUT_CPLX);

    if (ws_size >= 16384) {
        // FAST PATH: 2 kernels. Scratch: mag2[252] dbl + F[144] f32 in d_ws.
        double* mag2 = (double*)d_ws;
        float*  F    = (float*)(mag2 + NMAG);

        k_win_noise_F<<<NMAG + 1, 256, 0, stream>>>(lsr, lsi, mag2, F);
        if (cplx) k_fused<true ><<<NBLK, 384, 0, stream>>>(lsr, lsi, cs, mag2, F, out);
        else      k_fused<false><<<NBLK, 384, 0, stream>>>(lsr, lsi, cs, mag2, F, out);
    } else {
        // FALLBACK (R5-proven): scratch in the tail of d_out
        float* base = out + ((size_t)out_size - SCRATCH_F);
        double* mag2  = (double*)base;
        double* noise = mag2 + PP * NW;
        int*    peak  = (int*)(base + 2692);
        float*  F     = base + 2724;
        float*  havg  = base + 2868;
        float*  hint  = base + 55092;
        float*  resid = base + 263988;

        k_window_noise_fb<<<PP * NW + 1, 256, 0, stream>>>(lsr, lsi, cs, mag2, noise);
        k_peak_F_fb<<<1, 192, 0, stream>>>(cs, mag2, noise, peak, F);
        k_havg<<<(PP * GAVG + 255) / 256, 256, 0, stream>>>(lsr, lsi, peak, havg);
        k_interp<<<(PP * LL + 255) / 256, 256, 0, stream>>>(havg, hint);
        k_resid<<<(LL + 255) / 256, 256, 0, stream>>>(lsr, lsi, peak, hint, resid);
        if (cplx) {
            k_mmse<true><<<(PP * NBLK + 255) / 256, 256, 0, stream>>>(peak, hint, resid, F, out);
            const int tile_f4 = PP * LL * 2 / 4;
            k_tile<<<(tile_f4 + 255) / 256, 256, 0, stream>>>((float4*)out, tile_f4);
        } else {
            k_mmse<false><<<(PP * NBLK + 255) / 256, 256, 0, stream>>>(peak, hint, resid, F, out);
            const int tile_f4 = PP * LL / 4;
            k_tile<<<(tile_f4 + 255) / 256, 256, 0, stream>>>((float4*)out, tile_f4);
        }
    }
}